// Round 3
// baseline (602.195 us; speedup 1.0000x reference)
//
#include <hip/hip_runtime.h>
#include <math.h>

#define N_POS 8192
#define BATCH 4
#define N_GT 512
#define BG 2048
#define EPSV 1e-6f

#define KA_BLOCKS 1024
#define ROWS_A 8
#define KC_BLOCKS 1024
#define ROWS_C 8
#define RG 32                                // kD1 row-groups
#define CHUNKS_PER_RG (KC_BLOCKS / RG)       // 32

// workspace float offsets
// dpack layout: dpack[n][j], j = 8*t + k  (column j's batch = j>>9 = wave id of owner)
#define WS_DPACK 0                              // [8192][2048] = 64 MiB
#define WS_PARTS (N_POS * BG)                   // [1024][2048] = 8 MiB
#define WS_PARTS2 (WS_PARTS + KC_BLOCKS * BG)   // [32][2048] = 256 KiB
#define WS_MIND  (WS_PARTS2 + RG * BG)          // [4][8192] min_g D
#define WS_MAXP  (WS_MIND + BATCH * N_POS)      // [1024] kA block maxes
#define WS_SC    (WS_MAXP + KA_BLOCKS)          // [0]=maxd [1]=pmin [2]=prange [3..6]=n_est
                                                // [7..10]=t1 [11]=t2sum [12]=kD2 ticket [13]=kA ticket

typedef __attribute__((ext_vector_type(4))) float f32x4;

// ---------------- kA: pass over dis_matrix (pipelined) + fused scalar finalize ----------------
__global__ __launch_bounds__(256) void whd_kA(const float* __restrict__ dis,
                                              const int* __restrict__ gt,
                                              const float* __restrict__ prob,
                                              float* __restrict__ wsf) {
    __shared__ float rowbuf[N_POS];     // 32 KB
    __shared__ unsigned short gtl[BG];  // 4 KB
    __shared__ float smax[4];
    __shared__ float sA[4], sB[4], sC[4];
    __shared__ int sflag;
    const int t = threadIdx.x;
    const int wv = t >> 6, lane = t & 63;
    const int row0 = blockIdx.x * ROWS_A;
    float* dpack = wsf + WS_DPACK;
    float* minD = wsf + WS_MIND;

    for (int i = t; i < BG; i += 256) gtl[i] = (unsigned short)gt[i];

    // prefetch row0 into registers (nontemporal: dis is stream-once)
    f32x4 pre[8];
    {
        const f32x4* src = (const f32x4*)(dis + (size_t)row0 * N_POS);
        #pragma unroll
        for (int j = 0; j < 8; j++) pre[j] = __builtin_nontemporal_load(src + t + 256 * j);
    }
    __syncthreads();  // gtl ready
    int c[8];
    #pragma unroll
    for (int k = 0; k < 8; k++) c[k] = gtl[8 * t + k];

    float tmax = -INFINITY;
    for (int r = 0; r < ROWS_A; r++) {
        const int n = row0 + r;
        // drain prefetched row r into LDS, fold into running max
        f32x4* dstl = (f32x4*)rowbuf;
        #pragma unroll
        for (int j = 0; j < 8; j++) {
            f32x4 v = pre[j];
            tmax = fmaxf(tmax, fmaxf(fmaxf(v.x, v.y), fmaxf(v.z, v.w)));
            dstl[t + 256 * j] = v;
        }
        // issue loads for row r+1 now; latency hides under gather+barriers
        if (r + 1 < ROWS_A) {
            const f32x4* srcn = (const f32x4*)(dis + (size_t)(n + 1) * N_POS);
            #pragma unroll
            for (int j = 0; j < 8; j++) pre[j] = __builtin_nontemporal_load(srcn + t + 256 * j);
        }
        __syncthreads();  // rowbuf ready
        float g0 = rowbuf[c[0]], g1 = rowbuf[c[1]], g2 = rowbuf[c[2]], g3 = rowbuf[c[3]];
        float g4 = rowbuf[c[4]], g5 = rowbuf[c[5]], g6 = rowbuf[c[6]], g7 = rowbuf[c[7]];
        f32x4* dst = (f32x4*)(dpack + (size_t)n * BG + 8 * t);
        f32x4 pk0; pk0.x = g0; pk0.y = g1; pk0.z = g2; pk0.w = g3;
        f32x4 pk1; pk1.x = g4; pk1.y = g5; pk1.z = g6; pk1.w = g7;
        dst[0] = pk0;
        dst[1] = pk1;
        float m = fminf(fminf(fminf(g0, g1), fminf(g2, g3)),
                        fminf(fminf(g4, g5), fminf(g6, g7)));
        #pragma unroll
        for (int off = 32; off; off >>= 1) m = fminf(m, __shfl_xor(m, off, 64));
        if (lane == 0) minD[wv * N_POS + n] = m;
        if (r + 1 < ROWS_A) __syncthreads();  // gathers done before rowbuf overwrite
    }
    #pragma unroll
    for (int off = 32; off; off >>= 1) tmax = fmaxf(tmax, __shfl_down(tmax, off, 64));
    if (lane == 0) smax[wv] = tmax;
    __syncthreads();
    if (t == 0)
        wsf[WS_MAXP + blockIdx.x] = fmaxf(fmaxf(smax[0], smax[1]), fmaxf(smax[2], smax[3]));

    // ---- last-block-done ticket: finalize scalars inside this dispatch ----
    __threadfence();          // release this block's dpack/minD/MAXP writes
    __syncthreads();
    if (t == 0) {
        unsigned prev = atomicAdd((unsigned*)(wsf + WS_SC + 13), 1u);
        sflag = (prev == (unsigned)(KA_BLOCKS - 1)) ? 1 : 0;
    }
    __syncthreads();
    if (sflag) {
        __threadfence();      // acquire
        // maxdist over the 1024 block maxes (coherent reads)
        float m = -INFINITY;
        #pragma unroll 4
        for (int i = t; i < KA_BLOCKS; i += 256) m = fmaxf(m, atomicAdd(&wsf[WS_MAXP + i], 0.0f));
        // prob global min/max (input array: plain loads fine)
        float lmin = INFINITY, lmax = -INFINITY;
        const f32x4* p4 = (const f32x4*)prob;
        #pragma unroll 4
        for (int i = t; i < BATCH * N_POS / 4; i += 256) {
            f32x4 v = p4[i];
            lmin = fminf(fminf(lmin, fminf(v.x, v.y)), fminf(v.z, v.w));
            lmax = fmaxf(fmaxf(lmax, fmaxf(v.x, v.y)), fmaxf(v.z, v.w));
        }
        #pragma unroll
        for (int off = 32; off; off >>= 1) {
            m = fmaxf(m, __shfl_xor(m, off, 64));
            lmin = fminf(lmin, __shfl_xor(lmin, off, 64));
            lmax = fmaxf(lmax, __shfl_xor(lmax, off, 64));
        }
        if (lane == 0) { sA[wv] = m; sB[wv] = lmin; sC[wv] = lmax; }
        __syncthreads();
        const float maxd = fmaxf(fmaxf(sA[0], sA[1]), fmaxf(sA[2], sA[3]));
        const float mn = fminf(fminf(sB[0], sB[1]), fminf(sB[2], sB[3]));
        const float mx = fmaxf(fmaxf(sC[0], sC[1]), fmaxf(sC[2], sC[3]));
        const float invr = 1.0f / (mx - mn);
        // per-wave batch: n_est and sum p*minD (minD via coherent reads)
        const int b = wv;
        float sp = 0.f, spm = 0.f;
        #pragma unroll 8
        for (int i = lane; i < N_POS; i += 64) {
            float pv = (prob[b * N_POS + i] - mn) * invr;
            pv = fminf(fmaxf(pv, 0.f), 1.f);
            float dm = atomicAdd(&minD[b * N_POS + i], 0.0f);
            sp += pv; spm += pv * dm;
        }
        #pragma unroll
        for (int off = 32; off; off >>= 1) {
            sp += __shfl_xor(sp, off, 64);
            spm += __shfl_xor(spm, off, 64);
        }
        if (lane == 0) { wsf[WS_SC + 3 + b] = sp; wsf[WS_SC + 7 + b] = spm; }
        if (t == 0) {
            wsf[WS_SC + 0] = maxd;
            wsf[WS_SC + 1] = mn;
            wsf[WS_SC + 2] = mx - mn;
        }
    }
}

// ---------------- kC: reciprocal pass over packed columns ----------------
__global__ __launch_bounds__(256) void whd_kC(const float* __restrict__ prob,
                                              float* __restrict__ wsf) {
    const int t = threadIdx.x;
    const int wv = t >> 6;              // batch of all 8 owned columns
    const int row0 = blockIdx.x * ROWS_C;
    const float* dpack = wsf + WS_DPACK;
    const float maxd = wsf[WS_SC + 0];
    const float pmin = wsf[WS_SC + 1];
    const float invr = 1.0f / wsf[WS_SC + 2];
    float acc[8];
    #pragma unroll
    for (int k = 0; k < 8; k++) acc[k] = 0.f;
    #pragma unroll
    for (int r = 0; r < ROWS_C; r++) {
        const int n = row0 + r;
        float p = (prob[wv * N_POS + n] - pmin) * invr;
        p = fminf(fmaxf(p, 0.f), 1.f);
        const f32x4* rp = (const f32x4*)(dpack + (size_t)n * BG + 8 * t);
        f32x4 v0 = __builtin_nontemporal_load(rp);
        f32x4 v1 = __builtin_nontemporal_load(rp + 1);
        acc[0] += 1.0f / (fmaf(p, v0.x - maxd, maxd) + EPSV);
        acc[1] += 1.0f / (fmaf(p, v0.y - maxd, maxd) + EPSV);
        acc[2] += 1.0f / (fmaf(p, v0.z - maxd, maxd) + EPSV);
        acc[3] += 1.0f / (fmaf(p, v0.w - maxd, maxd) + EPSV);
        acc[4] += 1.0f / (fmaf(p, v1.x - maxd, maxd) + EPSV);
        acc[5] += 1.0f / (fmaf(p, v1.y - maxd, maxd) + EPSV);
        acc[6] += 1.0f / (fmaf(p, v1.z - maxd, maxd) + EPSV);
        acc[7] += 1.0f / (fmaf(p, v1.w - maxd, maxd) + EPSV);
    }
    f32x4* op = (f32x4*)(wsf + WS_PARTS + (size_t)blockIdx.x * BG + 8 * t);
    f32x4 o0; o0.x = acc[0]; o0.y = acc[1]; o0.z = acc[2]; o0.w = acc[3];
    f32x4 o1; o1.x = acc[4]; o1.y = acc[5]; o1.z = acc[6]; o1.w = acc[7];
    op[0] = o0;
    op[1] = o1;
}

// ---------------- kD1: coalesced partial-sum tree, stage 1 ----------------
__global__ __launch_bounds__(256) void whd_kD1(float* __restrict__ wsf) {
    const int t = threadIdx.x;
    const int col = blockIdx.x * 256 + t;
    const int rg = blockIdx.y;
    const float* parts = wsf + WS_PARTS + (size_t)rg * CHUNKS_PER_RG * BG;
    float s = 0.f;
    #pragma unroll 8
    for (int ch = 0; ch < CHUNKS_PER_RG; ch++) s += parts[(size_t)ch * BG + col];
    wsf[WS_PARTS2 + (size_t)rg * BG + col] = s;
}

// ---------------- kD2: finish column sums -> term2, last block finalizes out ----------------
__global__ __launch_bounds__(256) void whd_kD2(float* __restrict__ wsf,
                                               float* __restrict__ out) {
    __shared__ float red[4];
    const int t = threadIdx.x;
    const int col = blockIdx.x * 256 + t;
    const float* p2 = wsf + WS_PARTS2;
    float s = 0.f;
    #pragma unroll
    for (int rg = 0; rg < RG; rg++) s += p2[(size_t)rg * BG + col];
    float val = (float)N_POS / s;       // (mean_n 1/(w+eps))^-1
    #pragma unroll
    for (int off = 32; off; off >>= 1) val += __shfl_xor(val, off, 64);
    if ((t & 63) == 0) red[t >> 6] = val;
    __syncthreads();
    if (t == 0) {
        float blocksum = red[0] + red[1] + red[2] + red[3];
        atomicAdd(&wsf[WS_SC + 11], blocksum);
        __threadfence();
        unsigned prev = atomicAdd((unsigned*)(wsf + WS_SC + 12), 1u);
        if (prev == gridDim.x - 1) {
            float t2sum = atomicAdd(&wsf[WS_SC + 11], 0.0f);  // coherent read
            float term1 = 0.f;
            #pragma unroll
            for (int b = 0; b < BATCH; b++)
                term1 += wsf[WS_SC + 7 + b] / (wsf[WS_SC + 3 + b] + EPSV);
            out[0] = term1 * (1.0f / BATCH) + t2sum * (1.0f / BG);
        }
    }
}

extern "C" void kernel_launch(void* const* d_in, const int* in_sizes, int n_in,
                              void* d_out, int out_size, void* d_ws, size_t ws_size,
                              hipStream_t stream) {
    const float* prob = (const float*)d_in[0];   // (4, 8192) fp32
    const int* gt = (const int*)d_in[1];         // (4, 512) int32
    const float* dis = (const float*)d_in[2];    // (8192, 8192) fp32
    float* out = (float*)d_out;
    float* wsf = (float*)d_ws;

    // zero {t2 accum [11], kD2 ticket [12], kA ticket [13]} — 12 bytes
    hipMemsetAsync((char*)d_ws + (size_t)(WS_SC + 11) * sizeof(float), 0, 12, stream);
    whd_kA<<<KA_BLOCKS, 256, 0, stream>>>(dis, gt, prob, wsf);
    whd_kC<<<KC_BLOCKS, 256, 0, stream>>>(prob, wsf);
    whd_kD1<<<dim3(BG / 256, RG), 256, 0, stream>>>(wsf);
    whd_kD2<<<BG / 256, 256, 0, stream>>>(wsf, out);
}

// Round 5
// 397.431 us; speedup vs baseline: 1.5152x; 1.5152x over previous
//
#include <hip/hip_runtime.h>
#include <math.h>

#define N_POS 8192
#define BATCH 4
#define N_GT 512
#define BG 2048
#define EPSV 1e-6f

#define KA_BLOCKS 1024
#define ROWS_A 8
#define KC_BLOCKS 1024
#define ROWS_C 8
#define RG 32                                // kD1 row-groups
#define CHUNKS_PER_RG (KC_BLOCKS / RG)       // 32

// workspace float offsets
// dpack layout: dpack[n][j], j = gathered column index; batch of column j = j>>9
#define WS_DPACK 0                              // [8192][2048] = 64 MiB
#define WS_PARTS (N_POS * BG)                   // [1024][2048] = 8 MiB
#define WS_PARTS2 (WS_PARTS + KC_BLOCKS * BG)   // [32][2048] = 256 KiB
#define WS_MIND  (WS_PARTS2 + RG * BG)          // [4][8192] min_g D
#define WS_MAXP  (WS_MIND + BATCH * N_POS)      // [1024] kA block maxes
#define WS_SC    (WS_MAXP + KA_BLOCKS)          // [0]=maxd [1]=pmin [2]=prange [3..6]=n_est
                                                // [7..10]=t1 [11]=t2sum [12]=kD2 ticket

typedef __attribute__((ext_vector_type(4))) float f32x4;

// ---------------- kA: single pass over dis_matrix, 512 threads (full occupancy) ----------------
__global__ __launch_bounds__(512, 8) void whd_kA(const float* __restrict__ dis,
                                                 const int* __restrict__ gt,
                                                 float* __restrict__ wsf) {
    __shared__ float rowbuf[N_POS];     // 32 KB
    __shared__ unsigned short gtl[BG];  // 4 KB
    __shared__ float smax[8];
    __shared__ float smin[8];
    const int t = threadIdx.x;
    const int wv = t >> 6, lane = t & 63;
    const int row0 = blockIdx.x * ROWS_A;
    float* dpack = wsf + WS_DPACK;
    float* minD = wsf + WS_MIND;

    for (int i = t; i < BG; i += 512) gtl[i] = (unsigned short)gt[i];

    // prefetch row0 into registers (nontemporal: dis is stream-once)
    f32x4 pre[4];
    {
        const f32x4* src = (const f32x4*)(dis + (size_t)row0 * N_POS);
        #pragma unroll
        for (int j = 0; j < 4; j++) pre[j] = __builtin_nontemporal_load(src + t + 512 * j);
    }
    __syncthreads();  // gtl ready
    int c[4];
    #pragma unroll
    for (int k = 0; k < 4; k++) c[k] = gtl[4 * t + k];

    float tmax = -INFINITY;
    for (int r = 0; r < ROWS_A; r++) {
        const int n = row0 + r;
        // drain prefetched row r into LDS, fold into running max
        f32x4* dstl = (f32x4*)rowbuf;
        #pragma unroll
        for (int j = 0; j < 4; j++) {
            f32x4 v = pre[j];
            tmax = fmaxf(tmax, fmaxf(fmaxf(v.x, v.y), fmaxf(v.z, v.w)));
            dstl[t + 512 * j] = v;
        }
        // issue loads for row r+1 now; latency hides under gather+barriers
        if (r + 1 < ROWS_A) {
            const f32x4* srcn = (const f32x4*)(dis + (size_t)(n + 1) * N_POS);
            #pragma unroll
            for (int j = 0; j < 4; j++) pre[j] = __builtin_nontemporal_load(srcn + t + 512 * j);
        }
        __syncthreads();  // rowbuf ready
        float g0 = rowbuf[c[0]], g1 = rowbuf[c[1]], g2 = rowbuf[c[2]], g3 = rowbuf[c[3]];
        f32x4 pk; pk.x = g0; pk.y = g1; pk.z = g2; pk.w = g3;
        ((f32x4*)(dpack + (size_t)n * BG + 4 * t))[0] = pk;
        float m = fminf(fminf(g0, g1), fminf(g2, g3));
        #pragma unroll
        for (int off = 32; off; off >>= 1) m = fminf(m, __shfl_xor(m, off, 64));
        if (lane == 0) smin[wv] = m;
        __syncthreads();  // smin ready; rowbuf consumed (safe to overwrite next iter)
        if (t < BATCH) minD[t * N_POS + n] = fminf(smin[2 * t], smin[2 * t + 1]);
    }
    #pragma unroll
    for (int off = 32; off; off >>= 1) tmax = fmaxf(tmax, __shfl_down(tmax, off, 64));
    if (lane == 0) smax[wv] = tmax;
    __syncthreads();
    if (t == 0) {
        float m = smax[0];
        #pragma unroll
        for (int i = 1; i < 8; i++) m = fmaxf(m, smax[i]);
        wsf[WS_MAXP + blockIdx.x] = m;
    }
}

// ---------------- kB: finalize scalars + n_est/term1 (single block, shfl-reduced) ----------------
__global__ __launch_bounds__(1024) void whd_kB(const float* __restrict__ prob,
                                               float* __restrict__ wsf) {
    __shared__ float sA[16], sB[16], sC[16];
    const int t = threadIdx.x, wv = t >> 6, lane = t & 63;

    // maxdist over kA block maxes (KA_BLOCKS == 1024 -> one element per thread)
    float m = -INFINITY;
    for (int i = t; i < KA_BLOCKS; i += 1024) m = fmaxf(m, wsf[WS_MAXP + i]);
    #pragma unroll
    for (int off = 32; off; off >>= 1) m = fmaxf(m, __shfl_xor(m, off, 64));

    // fused prob min/max, float4 loads
    float lmin = INFINITY, lmax = -INFINITY;
    const f32x4* p4 = (const f32x4*)prob;
    for (int i = t; i < BATCH * N_POS / 4; i += 1024) {
        f32x4 v = p4[i];
        lmin = fminf(fminf(lmin, fminf(v.x, v.y)), fminf(v.z, v.w));
        lmax = fmaxf(fmaxf(lmax, fmaxf(v.x, v.y)), fmaxf(v.z, v.w));
    }
    #pragma unroll
    for (int off = 32; off; off >>= 1) {
        lmin = fminf(lmin, __shfl_xor(lmin, off, 64));
        lmax = fmaxf(lmax, __shfl_xor(lmax, off, 64));
    }
    if (lane == 0) { sA[wv] = m; sB[wv] = lmin; sC[wv] = lmax; }
    __syncthreads();
    if (t == 0) {
        float maxd = -INFINITY, mn = INFINITY, mx = -INFINITY;
        #pragma unroll
        for (int i = 0; i < 16; i++) {
            maxd = fmaxf(maxd, sA[i]); mn = fminf(mn, sB[i]); mx = fmaxf(mx, sC[i]);
        }
        wsf[WS_SC + 0] = maxd;
        wsf[WS_SC + 1] = mn;
        wsf[WS_SC + 2] = mx - mn;
        wsf[WS_SC + 11] = 0.f;   // t2 accumulator
        wsf[WS_SC + 12] = 0.f;   // kD2 ticket (bits == 0)
        sB[0] = mn; sC[0] = 1.0f / (mx - mn);
    }
    __syncthreads();
    const float pmin = sB[0], invr = sC[0];

    const f32x4* d4 = (const f32x4*)(wsf + WS_MIND);
    for (int b = 0; b < BATCH; b++) {
        float sp = 0.f, spm = 0.f;
        for (int i = t; i < N_POS / 4; i += 1024) {
            f32x4 v = p4[b * (N_POS / 4) + i];
            f32x4 dm = d4[b * (N_POS / 4) + i];
            float p;
            p = fminf(fmaxf((v.x - pmin) * invr, 0.f), 1.f); sp += p; spm += p * dm.x;
            p = fminf(fmaxf((v.y - pmin) * invr, 0.f), 1.f); sp += p; spm += p * dm.y;
            p = fminf(fmaxf((v.z - pmin) * invr, 0.f), 1.f); sp += p; spm += p * dm.z;
            p = fminf(fmaxf((v.w - pmin) * invr, 0.f), 1.f); sp += p; spm += p * dm.w;
        }
        #pragma unroll
        for (int off = 32; off; off >>= 1) {
            sp += __shfl_xor(sp, off, 64);
            spm += __shfl_xor(spm, off, 64);
        }
        __syncthreads();
        if (lane == 0) { sA[wv] = sp; sB[wv] = spm; }
        __syncthreads();
        if (t == 0) {
            float a = 0.f, c2 = 0.f;
            #pragma unroll
            for (int i = 0; i < 16; i++) { a += sA[i]; c2 += sB[i]; }
            wsf[WS_SC + 3 + b] = a;
            wsf[WS_SC + 7 + b] = c2;
        }
    }
}

// ---------------- kC: reciprocal pass over packed columns ----------------
__global__ __launch_bounds__(256) void whd_kC(const float* __restrict__ prob,
                                              float* __restrict__ wsf) {
    const int t = threadIdx.x;
    const int wv = t >> 6;              // batch of all 8 owned columns
    const int row0 = blockIdx.x * ROWS_C;
    const float* dpack = wsf + WS_DPACK;
    const float maxd = wsf[WS_SC + 0];
    const float pmin = wsf[WS_SC + 1];
    const float invr = 1.0f / wsf[WS_SC + 2];
    float acc[8];
    #pragma unroll
    for (int k = 0; k < 8; k++) acc[k] = 0.f;
    #pragma unroll
    for (int r = 0; r < ROWS_C; r++) {
        const int n = row0 + r;
        float p = (prob[wv * N_POS + n] - pmin) * invr;
        p = fminf(fmaxf(p, 0.f), 1.f);
        const f32x4* rp = (const f32x4*)(dpack + (size_t)n * BG + 8 * t);
        f32x4 v0 = __builtin_nontemporal_load(rp);
        f32x4 v1 = __builtin_nontemporal_load(rp + 1);
        acc[0] += 1.0f / (fmaf(p, v0.x - maxd, maxd) + EPSV);
        acc[1] += 1.0f / (fmaf(p, v0.y - maxd, maxd) + EPSV);
        acc[2] += 1.0f / (fmaf(p, v0.z - maxd, maxd) + EPSV);
        acc[3] += 1.0f / (fmaf(p, v0.w - maxd, maxd) + EPSV);
        acc[4] += 1.0f / (fmaf(p, v1.x - maxd, maxd) + EPSV);
        acc[5] += 1.0f / (fmaf(p, v1.y - maxd, maxd) + EPSV);
        acc[6] += 1.0f / (fmaf(p, v1.z - maxd, maxd) + EPSV);
        acc[7] += 1.0f / (fmaf(p, v1.w - maxd, maxd) + EPSV);
    }
    f32x4* op = (f32x4*)(wsf + WS_PARTS + (size_t)blockIdx.x * BG + 8 * t);
    f32x4 o0; o0.x = acc[0]; o0.y = acc[1]; o0.z = acc[2]; o0.w = acc[3];
    f32x4 o1; o1.x = acc[4]; o1.y = acc[5]; o1.z = acc[6]; o1.w = acc[7];
    op[0] = o0;
    op[1] = o1;
}

// ---------------- kD1: coalesced partial-sum tree, stage 1 ----------------
__global__ __launch_bounds__(256) void whd_kD1(float* __restrict__ wsf) {
    const int t = threadIdx.x;
    const int col = blockIdx.x * 256 + t;
    const int rg = blockIdx.y;
    const float* parts = wsf + WS_PARTS + (size_t)rg * CHUNKS_PER_RG * BG;
    float s = 0.f;
    #pragma unroll 8
    for (int ch = 0; ch < CHUNKS_PER_RG; ch++) s += parts[(size_t)ch * BG + col];
    wsf[WS_PARTS2 + (size_t)rg * BG + col] = s;
}

// ---------------- kD2: finish column sums -> term2, last block finalizes out ----------------
__global__ __launch_bounds__(256) void whd_kD2(float* __restrict__ wsf,
                                               float* __restrict__ out) {
    __shared__ float red[4];
    const int t = threadIdx.x;
    const int col = blockIdx.x * 256 + t;
    const float* p2 = wsf + WS_PARTS2;
    float s = 0.f;
    #pragma unroll
    for (int rg = 0; rg < RG; rg++) s += p2[(size_t)rg * BG + col];
    float val = (float)N_POS / s;       // (mean_n 1/(w+eps))^-1
    #pragma unroll
    for (int off = 32; off; off >>= 1) val += __shfl_xor(val, off, 64);
    if ((t & 63) == 0) red[t >> 6] = val;
    __syncthreads();
    if (t == 0) {
        float blocksum = red[0] + red[1] + red[2] + red[3];
        atomicAdd(&wsf[WS_SC + 11], blocksum);
        __threadfence();
        unsigned prev = atomicAdd((unsigned*)(wsf + WS_SC + 12), 1u);
        if (prev == gridDim.x - 1) {
            float t2sum = atomicAdd(&wsf[WS_SC + 11], 0.0f);  // coherent read
            float term1 = 0.f;
            #pragma unroll
            for (int b = 0; b < BATCH; b++)
                term1 += wsf[WS_SC + 7 + b] / (wsf[WS_SC + 3 + b] + EPSV);
            out[0] = term1 * (1.0f / BATCH) + t2sum * (1.0f / BG);
        }
    }
}

extern "C" void kernel_launch(void* const* d_in, const int* in_sizes, int n_in,
                              void* d_out, int out_size, void* d_ws, size_t ws_size,
                              hipStream_t stream) {
    const float* prob = (const float*)d_in[0];   // (4, 8192) fp32
    const int* gt = (const int*)d_in[1];         // (4, 512) int32
    const float* dis = (const float*)d_in[2];    // (8192, 8192) fp32
    float* out = (float*)d_out;
    float* wsf = (float*)d_ws;

    whd_kA<<<KA_BLOCKS, 512, 0, stream>>>(dis, gt, wsf);
    whd_kB<<<1, 1024, 0, stream>>>(prob, wsf);
    whd_kC<<<KC_BLOCKS, 256, 0, stream>>>(prob, wsf);
    whd_kD1<<<dim3(BG / 256, RG), 256, 0, stream>>>(wsf);
    whd_kD2<<<BG / 256, 256, 0, stream>>>(wsf, out);
}